// Round 1
// baseline (99.021 us; speedup 1.0000x reference)
//
#include <hip/hip_runtime.h>
#include <math.h>

// Problem constants (IMG=1024, B=2, A=20, levels i=2..6)
#define NANCH 261888          // anchors per batch = 3*(256^2+128^2+64^2+32^2+16^2)
#define NB 2
#define NGT 20

// Flat float32 output layout (concatenated in return order)
#define OFF_BOX   (2*NB*NANCH)                 // scores are [0, OFF_BOX)
#define OFF_ANC   (OFF_BOX + 4*NB*NANCH)
#define OFF_LAB   (OFF_ANC + 4*NB*NANCH)

__global__ __launch_bounds__(256) void rpn_fused(
    const float* __restrict__ cs2, const float* __restrict__ bp2,
    const float* __restrict__ cs3, const float* __restrict__ bp3,
    const float* __restrict__ cs4, const float* __restrict__ bp4,
    const float* __restrict__ cs5, const float* __restrict__ bp5,
    const float* __restrict__ cs6, const float* __restrict__ bp6,
    const float* __restrict__ gt,  const int* __restrict__ cnt_raw,
    float* __restrict__ out)
{
    // Stage GT boxes (+precomputed area) and counts in LDS
    __shared__ float sgt[NB*NGT*5];
    __shared__ int scnt[NB];
    int tid = threadIdx.x;
    if (tid < NB*NGT) {
        float g0 = gt[tid*4+0], g1 = gt[tid*4+1], g2 = gt[tid*4+2], g3 = gt[tid*4+3];
        sgt[tid*5+0] = g0; sgt[tid*5+1] = g1;
        sgt[tid*5+2] = g2; sgt[tid*5+3] = g3;
        sgt[tid*5+4] = (g2 - g0) * (g3 - g1);    // ga, same fp order as reference
    }
    if (tid == 0) {
        // gt_counts is int64 in the reference; harness may pass int32 or int64.
        // counts are >=1, so high-word-of-count0 == 0 uniquely identifies int64 layout.
        int w0 = cnt_raw[0], w1 = cnt_raw[1];
        if (w1 == 0) { scnt[0] = w0; scnt[1] = cnt_raw[2]; }   // int64: [lo0,hi0,lo1,hi1]
        else         { scnt[0] = w0; scnt[1] = w1; }           // int32: [c0,c1]
    }
    __syncthreads();

    int t = blockIdx.x * 256 + tid;
    if (t >= NB*NANCH) return;
    int b = (t >= NANCH) ? 1 : 0;
    int n = t - b*NANCH;

    // Level select (wave-uniform except at boundary waves)
    const float* cs; const float* bp;
    int off, lhw, lw; float s, hs, aw;
    if (n < 196608)      { cs=cs2; bp=bp2; off=0;      lhw=16; lw=8; s=4.f;  hs=1.5f;  aw=64.f;  }
    else if (n < 245760) { cs=cs3; bp=bp3; off=196608; lhw=14; lw=7; s=8.f;  hs=3.5f;  aw=128.f; }
    else if (n < 258048) { cs=cs4; bp=bp4; off=245760; lhw=12; lw=6; s=16.f; hs=7.5f;  aw=256.f; }
    else if (n < 261120) { cs=cs5; bp=bp5; off=258048; lhw=10; lw=5; s=32.f; hs=15.5f; aw=512.f; }
    else                 { cs=cs6; bp=bp6; off=261120; lhw=8;  lw=4; s=64.f; hs=31.5f; aw=1024.f;}

    int local = n - off;
    int a   = local >> lhw;              // anchor type 0..2
    int rem = local & ((1 << lhw) - 1);  // y*w + x
    int y   = rem >> lw;
    int x   = rem & ((1 << lw) - 1);
    int hw  = 1 << lhw;

    // scores (channel permute): cs[b, a*2+c, y, x]
    int cbase = ((b*6 + a*2) << lhw) + rem;
    float c0 = cs[cbase];
    float c1 = cs[cbase + hw];
    // deltas: bp[b, a*4+d, y, x]
    int dbase = ((b*12 + a*4) << lhw) + rem;
    float d0 = bp[dbase];
    float d1 = bp[dbase + hw];
    float d2 = bp[dbase + 2*hw];
    float d3 = bp[dbase + 3*hw];

    // anchors (exact in fp32)
    float cy = s * (float)y + hs;
    float cx = s * (float)x + hs;
    float hh = (a == 2) ? 2.f*aw : aw;
    float ww = (a == 0) ? 2.f*aw : aw;

    // apply deltas -> boxes (2% threshold; fma/expf fine here)
    float cyc = cy + d0*hh;
    float cxc = cx + d1*ww;
    float h2  = hh * expf(d2);
    float w2  = ww * expf(d3);

    int gi = b*NANCH + n;
    ((float2*)out)[gi]             = make_float2(c0, c1);
    ((float4*)(out + OFF_BOX))[gi] = make_float4(cyc - 0.5f*h2, cxc - 0.5f*w2,
                                                 cyc + 0.5f*h2, cxc + 0.5f*w2);
    ((float4*)(out + OFF_ANC))[gi] = make_float4(cy, cx, hh, ww);

    // labels — replicate reference fp32 op order exactly (no fma hazards in this path)
    float y1 = cy - hh*0.5f;     // h/2 == h*0.5 bit-exact
    float y2 = y1 + hh;
    float x1 = cx - ww*0.5f;
    float x2 = x1 + ww;
    float area = hh * ww;
    int cnt = scnt[b];
    const float* gp = &sgt[b*NGT*5];
    bool pos = false;
    for (int g = 0; g < cnt; ++g) {
        float gy1 = gp[g*5+0], gx1 = gp[g*5+1];
        float gy2 = gp[g*5+2], gx2 = gp[g*5+3];
        float ga  = gp[g*5+4];
        float yy1 = fminf(fmaxf(y1, gy1), gy2);
        float yy2 = fminf(fmaxf(y2, gy1), gy2);
        float xx1 = fminf(fmaxf(x1, gx1), gx2);
        float xx2 = fminf(fmaxf(x2, gx1), gx2);
        float inter = (yy2 - yy1) * (xx2 - xx1);
        float uni   = (area + ga) - inter;
        float iou   = inter / uni;     // IEEE div, no fast-math
        pos = pos || (iou >= 0.5f);
    }
    out[OFF_LAB + gi] = pos ? 1.0f : 0.0f;
}

extern "C" void kernel_launch(void* const* d_in, const int* in_sizes, int n_in,
                              void* d_out, int out_size, void* d_ws, size_t ws_size,
                              hipStream_t stream) {
    // setup_inputs() dict order: cs2,bp2,cs3,bp3,cs4,bp4,cs5,bp5,cs6,bp6,gt_bboxes,gt_counts,img_h,img_w
    const int total = NB * NANCH;               // 523,776 -> exactly 2046 blocks of 256
    rpn_fused<<<(total + 255) / 256, 256, 0, stream>>>(
        (const float*)d_in[0], (const float*)d_in[1],
        (const float*)d_in[2], (const float*)d_in[3],
        (const float*)d_in[4], (const float*)d_in[5],
        (const float*)d_in[6], (const float*)d_in[7],
        (const float*)d_in[8], (const float*)d_in[9],
        (const float*)d_in[10], (const int*)d_in[11],
        (float*)d_out);
}